// Round 1
// 103.001 us; speedup vs baseline: 1.0726x; 1.0726x over previous
//
#include <hip/hip_runtime.h>
#include <float.h>
#include <math.h>

// AdvancedLossFunction: total = 1.0*occ + 0.1*smooth + 0.01*sparse + 0.1*cons
// R14: MFMA-ized knn. t(i,j) = -2 p_i.q_j + |q_j|^2 computed by
// v_mfma_f32_32x32x16_bf16 with 2-way bf16 hi/lo split packing (K=14 of 16):
//   j-side Kvec: [Hx,Hx,Lx,Lx, Hy,Hy,Ly,Ly, Hz,Hz,Lz,Lz, wh,wl, 0,0]
//   i-side Kvec: [hx,lx,hx,lx, hy,ly,hy,ly, hz,lz,hz,lz,  1, 1, 0,0]
//   -> dot = (Hx+Lx)(hx+lx)+... + w  (all cross terms, err ~3e-4 < key quant 1.5e-3)
// Symmetric packing: any within-lane k-permutation shared by A and B cancels.
// C/D layout (HW-verified): col=lane&31 (i), row=(reg&3)+8*(reg>>2)+4*(lane>>5) (j)
//   -> reg-group g holds exactly quartet (2g + lanehalf): 4 consecutive j's.
// Group = QUARTET (4 j's), id = j/4 in [0,4096) = exactly the 12-bit key field.
// Coverage: {self,NN1..3} occupy <=4 quartets -> top-4 quartet keys cover them;
// merge decodes 4 quartets -> 16 candidates, exact d2 + index self-exclusion.
// knn VALU/pair: 4.6 -> ~2.3 (fmas moved to matrix pipe). CHUNKS 64->16
// (cand 16.8MB -> 4.2MB). Fill ~45us is harness ws poison (uncontrollable).

constexpr int   N_ = 16384;
constexpr int   F_ = 64;
constexpr float OCC_W = 1.0f, SMOOTH_W = 0.1f, SPARSE_W = 0.01f, CONS_W = 0.1f;
constexpr float EPS_ = 1e-7f;

constexpr int CHUNKS  = 16;
constexpr int CHUNK_J = N_ / CHUNKS;    // 1024 j's per chunk
constexpr int JTILES  = CHUNK_J / 32;   // 32 MFMA j-tiles per chunk
constexpr int IB      = 128;            // i's per block (4 waves x 32)
constexpr int IBLOCKS = N_ / IB;        // 128

typedef __attribute__((ext_vector_type(8)))  short bf16x8;
typedef __attribute__((ext_vector_type(16))) float f32x16;

union U128 { uint4 u; bf16x8 s; };

__device__ __forceinline__ void ins4f(float t, float& b0, float& b1, float& b2, float& b3) {
  // maintains b0<=b1<=b2<=b3
  float n0 = fminf(b0, t);
  float n1 = __builtin_amdgcn_fmed3f(b0, b1, t);
  float n2 = __builtin_amdgcn_fmed3f(b1, b2, t);
  float n3 = __builtin_amdgcn_fmed3f(b2, b3, t);
  b0 = n0; b1 = n1; b2 = n2; b3 = n3;
}

// RNE split x = hi + lo (both bf16); returns 16-bit payloads.
// hi err <= 2^-9|x|; lo captures residual exactly (Sterbenz), lo err <= 2^-18|x|.
__device__ __forceinline__ void split2(float x, unsigned& h16, unsigned& l16) {
  unsigned u = __float_as_uint(x);
  unsigned r = u + 0x7FFFu + ((u >> 16) & 1u);
  h16 = r >> 16;
  float lo = x - __uint_as_float(r & 0xFFFF0000u);
  unsigned v = __float_as_uint(lo);
  l16 = (v + 0x7FFFu + ((v >> 16) & 1u)) >> 16;
}

// ws layout: 0: float4 part[256] | 4096: unsigned done | 8192: float4 cand[CHUNKS][N]

__global__ __launch_bounds__(256) void knn_mfma(const float* __restrict__ pts,
                                                float4* __restrict__ cand,
                                                unsigned* __restrict__ done) {
  if (blockIdx.x == 0 && threadIdx.x == 0) *done = 0u;
  __shared__ uint4 AF[2][CHUNK_J];      // packed A-frag halves, 32 KB
  const int tid   = threadIdx.x;
  const int chunk = blockIdx.x & (CHUNKS - 1);
  const int ibk   = blockIdx.x >> 4;    // log2(CHUNKS)
  const int j0    = chunk * CHUNK_J;

  // Stage j-side fragments: per j, Kvec as 8 packed words (2 bf16 each).
  for (int t = tid; t < CHUNK_J; t += 256) {
    int j = j0 + t;
    float qx = pts[3 * j], qy = pts[3 * j + 1], qz = pts[3 * j + 2];
    float w  = fmaf(qx, qx, fmaf(qy, qy, qz * qz));
    unsigned Hx, Lx, Hy, Ly, Hz, Lz, Hw, Lw;
    split2(-2.f * qx, Hx, Lx);
    split2(-2.f * qy, Hy, Ly);
    split2(-2.f * qz, Hz, Lz);
    split2(w, Hw, Lw);
    AF[0][t] = make_uint4(Hx | (Hx << 16), Lx | (Lx << 16),
                          Hy | (Hy << 16), Ly | (Ly << 16));
    AF[1][t] = make_uint4(Hz | (Hz << 16), Lz | (Lz << 16),
                          Hw | (Lw << 16), 0u);
  }

  // i-side (B operand) fragment: resident for the whole kernel.
  const int lane = tid & 63, wv = tid >> 6;
  const int h = lane >> 5, il = lane & 31;
  const int i = ibk * IB + wv * 32 + il;
  U128 bf;
  {
    float x = pts[3 * i], y = pts[3 * i + 1], z = pts[3 * i + 2];
    unsigned hx, lx, hy, ly, hz, lz;
    split2(x, hx, lx);
    split2(y, hy, ly);
    split2(z, hz, lz);
    if (h == 0) {
      unsigned a = hx | (lx << 16), b = hy | (ly << 16);
      bf.u = make_uint4(a, a, b, b);
    } else {
      unsigned a = hz | (lz << 16);
      bf.u = make_uint4(a, a, 0x3F803F80u, 0u);   // bf16(1.0) pair
    }
  }
  __syncthreads();

  float b0 = FLT_MAX, b1 = FLT_MAX, b2 = FLT_MAX, b3 = FLT_MAX;
  const f32x16 zacc = {};                          // loop-invariant zero C operand
  const unsigned qb0 = (unsigned)(chunk * 256 + h);
  const uint4* __restrict__ afp = &AF[h][0];

#pragma unroll 4
  for (int t = 0; t < JTILES; ++t) {
    U128 af; af.u = afp[t * 32 + il];              // conflict-free b128
    f32x16 acc = __builtin_amdgcn_mfma_f32_32x32x16_bf16(af.s, bf.s, zacc, 0, 0, 0);
    unsigned q = qb0 + (unsigned)(t * 8);
#pragma unroll
    for (int g = 0; g < 4; ++g) {
      float m = fminf(fminf(acc[4 * g + 0], acc[4 * g + 1]),
                      fminf(acc[4 * g + 2], acc[4 * g + 3]));
      float kf = __uint_as_float((__float_as_uint(m) & 0xFFFFF000u) | (q + 2u * g));
      ins4f(kf, b0, b1, b2, b3);
    }
  }

  // merge the two lane-halves (same i, disjoint quartet sets)
  float o0 = __shfl_xor(b0, 32), o1 = __shfl_xor(b1, 32),
        o2 = __shfl_xor(b2, 32), o3 = __shfl_xor(b3, 32);
  ins4f(o0, b0, b1, b2, b3);
  ins4f(o1, b0, b1, b2, b3);
  ins4f(o2, b0, b1, b2, b3);
  ins4f(o3, b0, b1, b2, b3);
  if (h == 0) cand[(size_t)chunk * N_ + i] = make_float4(b0, b1, b2, b3);
}

// grid 256: 64 i's per block; 4 waves scan 4 chunks each; wave 0 merges, decodes
// 4 quartets -> 16 candidates, exact d2 + index self-exclusion -> smoothness.
__global__ __launch_bounds__(256) void merge_kernel(const float* __restrict__ pred,
                                                    const float* __restrict__ targ,
                                                    const float* __restrict__ feat,
                                                    const float* __restrict__ pts,
                                                    const float4* __restrict__ cand,
                                                    float4* __restrict__ part,
                                                    unsigned* __restrict__ done,
                                                    float* __restrict__ out) {
  __shared__ float4 sh[256];
  __shared__ float ws4[4][4];
  __shared__ int is_last;
  constexpr int CPT = CHUNKS / 4;                  // 4 chunks per sub-wave
  int tid  = threadIdx.x;
  int lane = tid & 63;
  int sub  = tid >> 6;
  int i = blockIdx.x * 64 + lane;

  const float4* f4 = (const float4*)feat;
  float s_sp = 0.f;
#pragma unroll
  for (int s = 0; s < 4; ++s) {
    float4 v = f4[(size_t)s * 65536 + blockIdx.x * 256 + tid];
    s_sp += fabsf(v.x) + fabsf(v.y) + fabsf(v.z) + fabsf(v.w);
  }

  float b0 = FLT_MAX, b1 = FLT_MAX, b2 = FLT_MAX, b3 = FLT_MAX;
#pragma unroll
  for (int cc = 0; cc < CPT; ++cc) {
    float4 v = cand[(size_t)(sub * CPT + cc) * N_ + i];
    ins4f(v.x, b0, b1, b2, b3);
    ins4f(v.y, b0, b1, b2, b3);
    ins4f(v.z, b0, b1, b2, b3);
    ins4f(v.w, b0, b1, b2, b3);
  }
  sh[tid] = make_float4(b0, b1, b2, b3);
  __syncthreads();

  float s_occ = 0.f, s_cons = 0.f, s_sm = 0.f;
  if (sub == 0) {
#pragma unroll
    for (int w = 1; w < 4; ++w) {
      float4 v = sh[w * 64 + lane];
      ins4f(v.x, b0, b1, b2, b3);
      ins4f(v.y, b0, b1, b2, b3);
      ins4f(v.z, b0, b1, b2, b3);
      ins4f(v.w, b0, b1, b2, b3);
    }
    unsigned qarr[4] = {__float_as_uint(b0) & 0xFFFu, __float_as_uint(b1) & 0xFFFu,
                        __float_as_uint(b2) & 0xFFFu, __float_as_uint(b3) & 0xFFFu};
    float xi = pts[3 * i], yi = pts[3 * i + 1], zi = pts[3 * i + 2];
    float c0 = FLT_MAX, c1 = FLT_MAX, c2 = FLT_MAX;
    float p0 = 0.f, p1 = 0.f, p2 = 0.f;
#pragma unroll
    for (int s = 0; s < 4; ++s) {
#pragma unroll
      for (int m = 0; m < 4; ++m) {
        int j = (int)(qarr[s] * 4 + m);            // quartet decode
        float dx = xi - pts[3 * j], dy = yi - pts[3 * j + 1], dz = zi - pts[3 * j + 2];
        float d2 = fmaf(dx, dx, fmaf(dy, dy, dz * dz));
        float pj = pred[j];
        if (j != i && d2 < c2) {                   // exact top-3, self excluded
          bool cc0 = d2 < c0, cc1 = d2 < c1;
          float n2 = cc1 ? c1 : d2;               float m2 = cc1 ? p1 : pj;
          float n1 = cc0 ? c0 : (cc1 ? d2 : c1);  float m1 = cc0 ? p0 : (cc1 ? pj : p1);
          float n0 = cc0 ? d2 : c0;               float m0 = cc0 ? pj : p0;
          c0 = n0; c1 = n1; c2 = n2; p0 = m0; p1 = m1; p2 = m2;
        }
      }
    }
    float pi = pred[i], tg = targ[i];
    float p  = fminf(fmaxf(pi, EPS_), 1.0f - EPS_);
    s_occ  = -(tg * __logf(p) + (1.0f - tg) * __logf(1.0f - p));
    float dd = pi - tg;
    s_cons = dd * dd;
    s_sm   = fabsf(pi - p0) + fabsf(pi - p1) + fabsf(pi - p2);
  }

  for (int off = 32; off > 0; off >>= 1) {
    s_sp   += __shfl_down(s_sp, off);
    s_occ  += __shfl_down(s_occ, off);
    s_cons += __shfl_down(s_cons, off);
    s_sm   += __shfl_down(s_sm, off);
  }
  if ((tid & 63) == 0) {
    int w = tid >> 6;
    ws4[w][0] = s_occ; ws4[w][1] = s_cons; ws4[w][2] = s_sp; ws4[w][3] = s_sm;
  }
  __syncthreads();
  if (tid == 0) {
    part[blockIdx.x] = make_float4(ws4[0][0] + ws4[1][0] + ws4[2][0] + ws4[3][0],
                                   ws4[0][1] + ws4[1][1] + ws4[2][1] + ws4[3][1],
                                   ws4[0][2] + ws4[1][2] + ws4[2][2] + ws4[3][2],
                                   ws4[0][3] + ws4[1][3] + ws4[2][3] + ws4[3][3]);
    __threadfence();
    unsigned prev = atomicAdd(done, 1u);
    is_last = (prev == (unsigned)(gridDim.x - 1));
  }
  __syncthreads();

  if (is_last) {
    __threadfence();
    float4 a = part[tid];
    float o = a.x, cn = a.y, sp = a.z, sm = a.w;
    for (int off = 32; off > 0; off >>= 1) {
      o  += __shfl_down(o, off);
      cn += __shfl_down(cn, off);
      sp += __shfl_down(sp, off);
      sm += __shfl_down(sm, off);
    }
    if ((tid & 63) == 0) {
      int w = tid >> 6;
      ws4[w][0] = o; ws4[w][1] = cn; ws4[w][2] = sp; ws4[w][3] = sm;
    }
    __syncthreads();
    if (tid == 0) {
      float occ  = ws4[0][0] + ws4[1][0] + ws4[2][0] + ws4[3][0];
      float cons = ws4[0][1] + ws4[1][1] + ws4[2][1] + ws4[3][1];
      float spar = ws4[0][2] + ws4[1][2] + ws4[2][2] + ws4[3][2];
      float smoo = ws4[0][3] + ws4[1][3] + ws4[2][3] + ws4[3][3];
      out[0] = OCC_W * (occ / (float)N_)
             + CONS_W * (cons / (float)N_)
             + SPARSE_W * (spar / (float)(N_ * F_))
             + SMOOTH_W * (smoo / (float)(N_ * 3));
    }
  }
}

extern "C" void kernel_launch(void* const* d_in, const int* in_sizes, int n_in,
                              void* d_out, int out_size, void* d_ws, size_t ws_size,
                              hipStream_t stream) {
  const float* pred = (const float*)d_in[0];
  const float* targ = (const float*)d_in[1];
  const float* feat = (const float*)d_in[2];
  const float* pts  = (const float*)d_in[3];
  float* out = (float*)d_out;

  char*     ws   = (char*)d_ws;
  float4*   part = (float4*)ws;
  unsigned* done = (unsigned*)(ws + 4096);
  float4*   cand = (float4*)(ws + 8192);

  knn_mfma<<<IBLOCKS * CHUNKS, 256, 0, stream>>>(pts, cand, done);
  merge_kernel<<<256, 256, 0, stream>>>(pred, targ, feat, pts, cand, part, done, out);
}